// Round 1
// baseline (150.041 us; speedup 1.0000x reference)
//
#include <hip/hip_runtime.h>
#include <cstdint>

#define BM 128
#define BN 64      // 63 real columns, padded
#define BK 32
#define TM 8
#define TN 4
#define KD 512
#define NSPLIT 63
#define NNODES 127

// GEMM (XA = x @ A^T) fused with heap-tree path-min epilogue.
// k-major swizzled LDS: element (k,row) at [k*LD + (row ^ (k & 28))].
// Swizzle bits are >=2 so float4 contiguity and 16B alignment are preserved.
__global__ __launch_bounds__(256, 4)
void lt_gemm_tree(const float* __restrict__ x, const float* __restrict__ A,
                  float* __restrict__ out) {
    __shared__ float sm[BM * 65];            // 33280 floats? no: 128*65 = 8320 floats = 33.3 KB
    float* xs = sm;                          // [BK][BM] swizzled  (4096 floats)
    float* bs = sm + BK * BM;                // [BK][BN] swizzled  (2048 floats)
    float* xa = sm;                          // epilogue reuse: [BM][65]

    const int tid = threadIdx.x;
    const int tx  = tid & 15;                // 0..15 -> cols 4*tx..+3
    const int ty  = tid >> 4;                // 0..15 -> rows 8*ty..+7
    const int r0  = blockIdx.x * BM;

    float acc[TM][TN];
#pragma unroll
    for (int i = 0; i < TM; ++i)
#pragma unroll
        for (int j = 0; j < TN; ++j) acc[i][j] = 0.f;

    for (int kc = 0; kc < KD / BK; ++kc) {
        // ---- stage x tile [BM x BK] (coalesced f4 loads, swizzled transposed writes)
#pragma unroll
        for (int p = 0; p < 4; ++p) {
            const int f4  = tid + p * 256;
            const int row = f4 >> 3;             // 0..127
            const int kj  = (f4 & 7) << 2;       // 0..28
            const float4 v = *reinterpret_cast<const float4*>(
                &x[(size_t)(r0 + row) * KD + kc * BK + kj]);
            const float vv[4] = {v.x, v.y, v.z, v.w};
#pragma unroll
            for (int c = 0; c < 4; ++c) {
                const int k = kj + c;
                xs[k * BM + (row ^ (k & 28))] = vv[c];
            }
        }
        // ---- stage A tile [BN x BK] (row 63 zero-padded)
#pragma unroll
        for (int p = 0; p < 2; ++p) {
            const int f4  = tid + p * 256;
            const int col = f4 >> 3;             // 0..63
            const int kj  = (f4 & 7) << 2;
            float4 v = make_float4(0.f, 0.f, 0.f, 0.f);
            if (col < NSPLIT)
                v = *reinterpret_cast<const float4*>(
                    &A[(size_t)col * KD + kc * BK + kj]);
            const float vv[4] = {v.x, v.y, v.z, v.w};
#pragma unroll
            for (int c = 0; c < 4; ++c) {
                const int k = kj + c;
                bs[k * BN + (col ^ (k & 28))] = vv[c];
            }
        }
        __syncthreads();

        // ---- inner product: per kk, 3x ds_read_b128 + 32 FMA
#pragma unroll 8
        for (int kk = 0; kk < BK; ++kk) {
            const int sw = kk & 28;
            const float4 a0 = *reinterpret_cast<const float4*>(
                &xs[kk * BM + ((ty * 8) ^ sw)]);
            const float4 a1 = *reinterpret_cast<const float4*>(
                &xs[kk * BM + ((ty * 8 + 4) ^ sw)]);
            const float4 b0 = *reinterpret_cast<const float4*>(
                &bs[kk * BN + ((tx * 4) ^ sw)]);
            const float a[TM] = {a0.x, a0.y, a0.z, a0.w, a1.x, a1.y, a1.z, a1.w};
            const float b[TN] = {b0.x, b0.y, b0.z, b0.w};
#pragma unroll
            for (int i = 0; i < TM; ++i)
#pragma unroll
                for (int j = 0; j < TN; ++j)
                    acc[i][j] = fmaf(a[i], b[j], acc[i][j]);
        }
        __syncthreads();
    }

    // ---- dump XA tile to LDS [BM][65] (+1 pad -> conflict-free column reads)
#pragma unroll
    for (int i = 0; i < TM; ++i)
#pragma unroll
        for (int j = 0; j < TN; ++j)
            xa[(ty * 8 + i) * 65 + tx * 4 + j] = acc[i][j];
    __syncthreads();

    // ---- tree path-min epilogue: 2 threads per row, h = which 64-node half to store
    const int r = tid >> 1;                  // 0..127
    const int h = tid & 1;
    float* orow = out + (size_t)(r0 + r) * NNODES;

    float q[NNODES];                         // fully unrolled -> stays in registers
    q[0] = 1.f;
    if (h == 0) orow[0] = 1.f;
#pragma unroll
    for (int t = 0; t < NSPLIT; ++t) {
        const float s  = xa[r * 65 + t];
        const float ql = fminf(q[t], s);
        const float qr = fminf(q[t], -s);
        q[2 * t + 1] = ql;
        q[2 * t + 2] = qr;
        const float zl = fminf(fmaxf(ql, 0.f), 1.f);
        const float zr = fminf(fmaxf(qr, 0.f), 1.f);
        if (2 * t + 1 < 64) { if (h == 0) orow[2 * t + 1] = zl; }
        else                { if (h == 1) orow[2 * t + 1] = zl; }
        if (2 * t + 2 < 64) { if (h == 0) orow[2 * t + 2] = zr; }
        else                { if (h == 1) orow[2 * t + 2] = zr; }
    }
}

extern "C" void kernel_launch(void* const* d_in, const int* in_sizes, int n_in,
                              void* d_out, int out_size, void* d_ws, size_t ws_size,
                              hipStream_t stream) {
    const float* x = (const float*)d_in[0];   // [131072, 512]
    const float* A = (const float*)d_in[1];   // [63, 512]
    float* out = (float*)d_out;               // [131072, 127]
    const int nrows = in_sizes[0] / KD;       // 131072
    const int grid = nrows / BM;              // 1024
    lt_gemm_tree<<<dim3(grid), dim3(256), 0, stream>>>(x, A, out);
}

// Round 2
// 96.598 us; speedup vs baseline: 1.5533x; 1.5533x over previous
//
#include <hip/hip_runtime.h>
#include <cstdint>

#define KD 512
#define BM 256
#define BK 32
#define NSPLIT 63
#define NNODES 127
#define NTHREADS 512
#define LDX 40          // staged-tile row stride in ushorts (80 B: 16B-aligned, ~2-way banks)

typedef __attribute__((ext_vector_type(8))) short bf16x8;
typedef __attribute__((ext_vector_type(4))) float f32x4;

__device__ __forceinline__ unsigned short bf16_rtn(float f) {
    unsigned u = __builtin_bit_cast(unsigned int, f);
    u += 0x7FFFu + ((u >> 16) & 1u);
    return (unsigned short)(u >> 16);
}
__device__ __forceinline__ float bf16_f32(unsigned short h) {
    unsigned u = (unsigned)h << 16;
    return __builtin_bit_cast(float, u);
}

// x @ A^T via split-bf16 MFMA (hi*hi + hi*lo + lo*hi), fused tree-min epilogue.
__global__ __launch_bounds__(NTHREADS, 2)
void lt_mfma_tree(const float* __restrict__ x, const float* __restrict__ A,
                  float* __restrict__ out) {
    __shared__ __align__(16) unsigned short sm[2 * BM * LDX + 2 * 64 * LDX];
    unsigned short* xh = sm;                    // [256][40]
    unsigned short* xl = sm + BM * LDX;         // [256][40]
    unsigned short* bh = sm + 2 * BM * LDX;     // [64][40]  (B = A^T stored [n][k])
    unsigned short* bl = bh + 64 * LDX;
    float* fl = reinterpret_cast<float*>(sm);   // epilogue alias: per-wave [16][65]

    const int tid = threadIdx.x;
    const int r0 = blockIdx.x * BM;

    // staging assignment: 2 threads per x-row (16 k each), 8 threads per A-row
    const int srow = tid >> 1;            // 0..255
    const int skh  = (tid & 1) * 16;      // 0 / 16
    const int bn   = tid >> 3;            // 0..63
    const int bkq  = (tid & 7) * 4;       // 0,4,..,28

    float xr[16];
    float br[4] = {0.f, 0.f, 0.f, 0.f};

    // prologue: load K-tile 0 into regs
    {
        const float* px = &x[(size_t)(r0 + srow) * KD + skh];
#pragma unroll
        for (int p = 0; p < 4; ++p)
            *reinterpret_cast<float4*>(&xr[p * 4]) =
                *reinterpret_cast<const float4*>(&px[p * 4]);
        if (bn < NSPLIT)
            *reinterpret_cast<float4*>(br) =
                *reinterpret_cast<const float4*>(&A[(size_t)bn * KD + bkq]);
    }

    const int wave = tid >> 6;
    const int lane = tid & 63;
    const int m0   = wave * 32;           // wave's 32-row slab
    const int fr   = lane & 15;           // fragment row/col within 16
    const int kb   = (lane >> 4) * 8;     // fragment k-base

    f32x4 acc[2][4];
#pragma unroll
    for (int i = 0; i < 2; ++i)
#pragma unroll
        for (int j = 0; j < 4; ++j) acc[i][j] = (f32x4)(0.f);

    for (int kc = 0; kc < KD / BK; ++kc) {
        // ---- convert tile regs -> bf16 hi/lo, stage to LDS (packed 16B writes)
        unsigned hw[8], lw[8];
#pragma unroll
        for (int i = 0; i < 8; ++i) {
            const unsigned short h0 = bf16_rtn(xr[2 * i]);
            const unsigned short h1 = bf16_rtn(xr[2 * i + 1]);
            const unsigned short l0 = bf16_rtn(xr[2 * i]     - bf16_f32(h0));
            const unsigned short l1 = bf16_rtn(xr[2 * i + 1] - bf16_f32(h1));
            hw[i] = (unsigned)h0 | ((unsigned)h1 << 16);
            lw[i] = (unsigned)l0 | ((unsigned)l1 << 16);
        }
        {
            int4 v;
            v.x = hw[0]; v.y = hw[1]; v.z = hw[2]; v.w = hw[3];
            *reinterpret_cast<int4*>(&xh[srow * LDX + skh]) = v;
            v.x = hw[4]; v.y = hw[5]; v.z = hw[6]; v.w = hw[7];
            *reinterpret_cast<int4*>(&xh[srow * LDX + skh + 8]) = v;
            v.x = lw[0]; v.y = lw[1]; v.z = lw[2]; v.w = lw[3];
            *reinterpret_cast<int4*>(&xl[srow * LDX + skh]) = v;
            v.x = lw[4]; v.y = lw[5]; v.z = lw[6]; v.w = lw[7];
            *reinterpret_cast<int4*>(&xl[srow * LDX + skh + 8]) = v;
        }
#pragma unroll
        for (int i = 0; i < 4; ++i) {
            const unsigned short h = bf16_rtn(br[i]);
            bh[bn * LDX + bkq + i] = h;
            bl[bn * LDX + bkq + i] = bf16_rtn(br[i] - bf16_f32(h));
        }
        __syncthreads();

        // ---- issue NEXT tile's global loads (overlap with MFMA below)
        if (kc + 1 < KD / BK) {
            const float* px = &x[(size_t)(r0 + srow) * KD + (kc + 1) * BK + skh];
#pragma unroll
            for (int p = 0; p < 4; ++p)
                *reinterpret_cast<float4*>(&xr[p * 4]) =
                    *reinterpret_cast<const float4*>(&px[p * 4]);
            if (bn < NSPLIT)
                *reinterpret_cast<float4*>(br) =
                    *reinterpret_cast<const float4*>(&A[(size_t)bn * KD + (kc + 1) * BK + bkq]);
        }

        // ---- MFMA: 2 m-frags x 4 n-frags x {hh, hl, lh}
        bf16x8 ah[2], al[2];
#pragma unroll
        for (int mf = 0; mf < 2; ++mf) {
            const int r = (m0 + mf * 16 + fr) * LDX + kb;
            ah[mf] = *reinterpret_cast<const bf16x8*>(&xh[r]);
            al[mf] = *reinterpret_cast<const bf16x8*>(&xl[r]);
        }
#pragma unroll
        for (int nf = 0; nf < 4; ++nf) {
            const int c = (nf * 16 + fr) * LDX + kb;
            const bf16x8 bhv = *reinterpret_cast<const bf16x8*>(&bh[c]);
            const bf16x8 blv = *reinterpret_cast<const bf16x8*>(&bl[c]);
#pragma unroll
            for (int mf = 0; mf < 2; ++mf) {
                acc[mf][nf] = __builtin_amdgcn_mfma_f32_16x16x32_bf16(ah[mf], bhv, acc[mf][nf], 0, 0, 0);
                acc[mf][nf] = __builtin_amdgcn_mfma_f32_16x16x32_bf16(ah[mf], blv, acc[mf][nf], 0, 0, 0);
                acc[mf][nf] = __builtin_amdgcn_mfma_f32_16x16x32_bf16(al[mf], bhv, acc[mf][nf], 0, 0, 0);
            }
        }
        __syncthreads();
    }

    // ---- epilogue: per wave, two phases of 16 rows via LDS [16][65] (reuses staging)
    const int drow = (lane >> 4) * 4;     // D-frag: row = drow+reg, col = fr
    float* warea = fl + wave * 16 * 65;
    const int trow = lane >> 2;           // 4 lanes per row
    const int part = lane & 3;            // each lane stores nodes [part*32, part*32+32)

#pragma unroll
    for (int ph = 0; ph < 2; ++ph) {
#pragma unroll
        for (int nf = 0; nf < 4; ++nf)
#pragma unroll
            for (int rg = 0; rg < 4; ++rg)
                warea[(drow + rg) * 65 + nf * 16 + fr] = acc[ph][nf][rg];
        __syncthreads();

        const float* srowp = warea + trow * 65;
        float* orow = out + (size_t)(r0 + m0 + ph * 16 + trow) * NNODES;
        float q[NNODES];                  // fully static indices -> registers
        q[0] = 1.f;
        if (part == 0) orow[0] = 1.f;
#pragma unroll
        for (int t = 0; t < NSPLIT; ++t) {
            const float s  = srowp[t];
            const float ql = fminf(q[t], s);
            const float qr = fminf(q[t], -s);
            q[2 * t + 1] = ql;
            q[2 * t + 2] = qr;
            const float zl = fminf(fmaxf(ql, 0.f), 1.f);
            const float zr = fminf(fmaxf(qr, 0.f), 1.f);
            if (((2 * t + 1) >> 5) == part) orow[2 * t + 1] = zl;
            if (((2 * t + 2) >> 5) == part) orow[2 * t + 2] = zr;
        }
        __syncthreads();
    }
}

extern "C" void kernel_launch(void* const* d_in, const int* in_sizes, int n_in,
                              void* d_out, int out_size, void* d_ws, size_t ws_size,
                              hipStream_t stream) {
    const float* x = (const float*)d_in[0];   // [131072, 512]
    const float* A = (const float*)d_in[1];   // [63, 512]
    float* out = (float*)d_out;               // [131072, 127]
    const int nrows = in_sizes[0] / KD;       // 131072
    const int grid = nrows / BM;              // 512
    lt_mfma_tree<<<dim3(grid), dim3(NTHREADS), 0, stream>>>(x, A, out);
}